// Round 1
// 233.017 us; speedup vs baseline: 1.0344x; 1.0344x over previous
//
#include <hip/hip_runtime.h>
#include <hip/hip_fp16.h>
#include <math.h>

// ---------------------------------------------------------------------------
// GNN pool: 2x GCNConv(elu) + MLP(128) + Linear(15) + softmax
// N=100000, E=3200000, IN=3, HID=64, MLP_HID=128, K=15, fp32 in/out.
//
// Round-15 pipeline (6 dispatches incl. memset):
//   memset cursor -> scatter512 (+prep block) -> csr_sort512 -> agg3
//   -> agg64 (NEW: 1 node/wave, 8 lanes/edge, dwordx4 row gathers)
//   -> h1 (all-MFMA + shfl softmax, r13)
//
// r15 theory: r14 (VALU trim) was neutral -> agg64 is LATENCY-bound
// (all counters <40%: VALU 38, HBM 35, Mfma 0, occ 68). Old structure
// serialized colb->gather->acc per 8-edge iteration (~5 x ~900cy/wave).
// New agg64: lane = 8*edge_slot + feature_octet; one dwordx4 per lane
// covers a full 128B s1h row across 8 lanes -> 8 edges per gather instr,
// no loop-carried dep, whole node's gathers issue in one burst. Self-loop
// folded in as slot ne (c=d). Feature reduction = 3-stage shfl_xor tree.
// Bytes/lines unchanged; only dependency structure + instr count change.
// ---------------------------------------------------------------------------

#define SPAN 128          // nodes per bucket
#define CAP  4608         // bucket capacity (mean 4092 + ~8 sigma)
#define CH   8192         // edges per scatter chunk (391 chunks)
#define EPT  16           // edges per thread in scatter (512 threads)
#define H2P  88           // h2s row pad (halfs)
#define MSP2 136          // ms row pad (halfs)

typedef _Float16 v8hf __attribute__((ext_vector_type(8)));
typedef float    v4f  __attribute__((ext_vector_type(4)));

__device__ __forceinline__ float elu(float v) { return v > 0.f ? v : expm1f(v); }

// ---- scatter (512 thr): edges -> buckets by dst>>7; last block = weight prep ----
__global__ __launch_bounds__(512) void scatter_kernel(const int* __restrict__ src,
    const int* __restrict__ dst, int* __restrict__ cursor, unsigned* __restrict__ colb,
    const float* __restrict__ W2, const float* __restrict__ Wm1,
    const float* __restrict__ Wm2, __half* __restrict__ W2t,
    __half* __restrict__ Wm1t, __half* __restrict__ Wm2p,
    int E, int NBK, int nChunks) {
    int tid = threadIdx.x;
    if ((int)blockIdx.x == nChunks) {   // ---- prep block ----
        for (int i = tid; i < 64 * 64; i += 512) {
            int f = i >> 6, k = i & 63;
            W2t[f * 64 + k] = __float2half(W2[k * 64 + f]);
        }
        for (int i = tid; i < 128 * 64; i += 512) {
            int j = i >> 6, f = i & 63;
            Wm1t[j * 64 + f] = __float2half(Wm1[f * 128 + j]);
        }
        for (int i = tid; i < 4 * 64 * 8; i += 512) {
            int j = i & 7, l = (i >> 3) & 63, t = i >> 9;
            int k = t * 32 + (l >> 4) * 8 + j;
            int c = l & 15;
            Wm2p[i] = (c < 15) ? __float2half(Wm2[k * 15 + c]) : __half(0.f);
        }
        return;
    }
    __shared__ int hist[1024];
    __shared__ unsigned gb[1024];
    int chunk = blockIdx.x;
    for (int i = tid; i < NBK; i += 512) hist[i] = 0;
    __syncthreads();
    int base = chunk * CH;
    int cnt = min(CH, E - base);
    unsigned br[EPT], dt[EPT];
#pragma unroll
    for (int j = 0; j < EPT; ++j) {
        int idx = j * 512 + tid;
        br[j] = 0xFFFFFFFFu;
        if (idx < cnt) {
            int e = base + idx;
            int s = src[e], d = dst[e];
            int b = d >> 7;
            int r = atomicAdd(&hist[b], 1);
            br[j] = ((unsigned)b << 13) | (unsigned)r;   // b<1024(10b), r<8192(13b)
            dt[j] = ((unsigned)(d & 127) << 17) | (unsigned)s;
        }
    }
    __syncthreads();
    for (int b = tid; b < NBK; b += 512) {
        int c = hist[b];
        gb[b] = (unsigned)(b * CAP) + (c ? (unsigned)atomicAdd(&cursor[b], c) : 0u);
    }
    __syncthreads();
#pragma unroll
    for (int j = 0; j < EPT; ++j) {
        if (br[j] != 0xFFFFFFFFu) {
            int b = br[j] >> 13;
            int r = br[j] & 8191;
            unsigned pos = gb[b] + (unsigned)r;
            if (pos < (unsigned)(b + 1) * CAP) colb[pos] = dt[j];
        }
    }
}

// ---- per-bucket counting sort IN PLACE (padded layout), rp2, dis, sxh ----
__global__ __launch_bounds__(512) void csr_sort_kernel(unsigned* __restrict__ colb,
    const int* __restrict__ cursor, const float* __restrict__ x,
    uint2* __restrict__ rp2, float* __restrict__ dis, __half* __restrict__ sxh,
    int N) {
    __shared__ __align__(16) unsigned ebuf[CAP];
    __shared__ __align__(16) int sbuf[CAP];
    __shared__ int cnt[SPAN], pref[SPAN], fill[SPAN];
    int b = blockIdx.x, tid = threadIdx.x;
    int n = min(cursor[b], CAP);
    size_t base = (size_t)b * CAP;
    if (tid < SPAN) cnt[tid] = 0;
    int n4 = n >> 2;
    for (int k = tid; k < n4; k += 512)
        *(uint4*)(ebuf + 4 * k) = *(const uint4*)(colb + base + 4 * k);
    for (int i = (n4 << 2) + tid; i < n; i += 512) ebuf[i] = colb[base + i];
    __syncthreads();
    for (int i = tid; i < n; i += 512) atomicAdd(&cnt[(ebuf[i] >> 17) & 127], 1);
    __syncthreads();
    if (tid < SPAN) pref[tid] = cnt[tid];
    __syncthreads();
    for (int off = 1; off < SPAN; off <<= 1) {
        int xv = (tid < SPAN && tid >= off) ? pref[tid - off] : 0;
        __syncthreads();
        if (tid < SPAN) pref[tid] += xv;
        __syncthreads();
    }
    if (tid < SPAN) {
        int ex = pref[tid] - cnt[tid];
        fill[tid] = ex;
        int node = b * SPAN + tid;
        if (node < N) {
            uint2 rp;
            rp.x = (unsigned)(base + ex);
            rp.y = (unsigned)(base + ex + cnt[tid]);
            rp2[node] = rp;
            float r = rsqrtf((float)(cnt[tid] + 1));
            dis[node] = r;
            __half2 h0 = __floats2half2_rn(r * x[node * 3 + 0], r * x[node * 3 + 1]);
            __half2 h1 = __floats2half2_rn(r * x[node * 3 + 2], 0.f);
            uint2 w; w.x = *(unsigned*)&h0; w.y = *(unsigned*)&h1;
            *(uint2*)(sxh + (size_t)node * 4) = w;
        }
    }
    __syncthreads();
    for (int i = tid; i < n; i += 512) {
        unsigned e = ebuf[i];
        int pos = atomicAdd(&fill[(e >> 17) & 127], 1);
        sbuf[pos] = (int)(e & 0x1FFFF);
    }
    __syncthreads();
    for (int k = tid; k < n4; k += 512)
        *(uint4*)(colb + base + 4 * k) = *(const uint4*)(sbuf + 4 * k);
    for (int i = (n4 << 2) + tid; i < n; i += 512) colb[base + i] = (unsigned)sbuf[i];
}

// ---- layer 1: 2 nodes/wave (32 lanes each), 8B gathers; s1h fp16 ----
__global__ void agg3_kernel(const __half* __restrict__ sxh, const uint2* __restrict__ rp2,
                            const unsigned* __restrict__ colb, const float* __restrict__ dis,
                            const float* __restrict__ W1, const float* __restrict__ b1,
                            __half* __restrict__ s1h, int N) {
    int wave = (blockIdx.x * blockDim.x + threadIdx.x) >> 6;
    int lane = threadIdx.x & 63;
    int hl = lane & 31;
    int d = wave * 2 + (lane >> 5);
    bool act = d < N;
    int start = 0, end = 0;
    if (act) { uint2 rp = rp2[d]; start = (int)rp.x; end = (int)rp.y; }
    float a0 = 0.f, a1 = 0.f, a2v = 0.f;
    for (int i = start + hl; i < end; i += 32) {
        uint2 rq = *(const uint2*)(sxh + (size_t)colb[i] * 4);
        float2 u0 = __half22float2(*(__half2*)&rq.x);
        float2 u1 = __half22float2(*(__half2*)&rq.y);
        a0 += u0.x; a1 += u0.y; a2v += u1.x;
    }
#pragma unroll
    for (int off = 16; off; off >>= 1) {
        a0  += __shfl_xor(a0, off);
        a1  += __shfl_xor(a1, off);
        a2v += __shfl_xor(a2v, off);
    }
    if (act) {
        uint2 rq = *(const uint2*)(sxh + (size_t)d * 4);   // self loop
        float2 u0 = __half22float2(*(__half2*)&rq.x);
        float2 u1 = __half22float2(*(__half2*)&rq.y);
        a0 += u0.x; a1 += u0.y; a2v += u1.x;
        float r = dis[d];
        float v0 = r * (a0 * W1[hl]      + a1 * W1[64 + hl]      + a2v * W1[128 + hl])      + b1[hl];
        float v1 = r * (a0 * W1[32 + hl] + a1 * W1[96 + hl]      + a2v * W1[160 + hl])      + b1[32 + hl];
        s1h[(size_t)d * 64 + hl]      = __float2half(r * elu(v0));
        s1h[(size_t)d * 64 + 32 + hl] = __float2half(r * elu(v1));
    }
}

// ---- layer 2 (r15): 1 node/wave; lane = 8*slot + octet; dwordx4 row gathers ----
// Slot j in [0,ne) = real edge, slot ne = self loop, slot > ne = masked.
// Per pair-chunk: 2 colb dwords + 2 dwordx4 gathers (16B/lane, 8 edges/instr).
// fp16 pair-add (same numerics class as r14), fp32 accumulate, fp32 shfl tree.
__global__ void agg64_kernel(const __half* __restrict__ s1h, const uint2* __restrict__ rp2,
                             const unsigned* __restrict__ colb, const float* __restrict__ dis,
                             __half* __restrict__ a2h, int N) {
    int wave = (blockIdx.x * blockDim.x + threadIdx.x) >> 6;
    int lane = threadIdx.x & 63;
    int g = lane >> 3;          // edge slot within chunk (0..7)
    int f = lane & 7;           // feature octet: halfs f*8 .. f*8+7 (16B)
    int d = wave;
    if (d >= N) return;
    uint2 rp = rp2[d];
    int start = (int)rp.x;
    int ne = (int)(rp.y - rp.x);       // real in-edges
    int nslots = ne + 1;               // + self loop at slot ne
    int npair = (nslots + 15) >> 4;    // 16-slot pair-chunks
    float acc0 = 0.f, acc1 = 0.f, acc2 = 0.f, acc3 = 0.f;
    float acc4 = 0.f, acc5 = 0.f, acc6 = 0.f, acc7 = 0.f;
    for (int p = 0; p < npair; ++p) {
        int ja = p * 16 + g;
        int jb = ja + 8;
        int ca = (int)colb[start + ja];    // padded alloc; garbage masked below
        int cb = (int)colb[start + jb];
        bool oa = ja < nslots, ob = jb < nslots;
        ca = (ja < ne) ? ca : d;           // slot ne -> self; beyond -> safe dummy
        cb = (jb < ne) ? cb : d;
        uint4 A = *(const uint4*)(s1h + (size_t)ca * 64 + f * 8);
        uint4 B = *(const uint4*)(s1h + (size_t)cb * 64 + f * 8);
        A.x = oa ? A.x : 0u; A.y = oa ? A.y : 0u;
        A.z = oa ? A.z : 0u; A.w = oa ? A.w : 0u;
        B.x = ob ? B.x : 0u; B.y = ob ? B.y : 0u;
        B.z = ob ? B.z : 0u; B.w = ob ? B.w : 0u;
        __half2 p0 = __hadd2(*(__half2*)&A.x, *(__half2*)&B.x);
        __half2 p1 = __hadd2(*(__half2*)&A.y, *(__half2*)&B.y);
        __half2 p2 = __hadd2(*(__half2*)&A.z, *(__half2*)&B.z);
        __half2 p3 = __hadd2(*(__half2*)&A.w, *(__half2*)&B.w);
        float2 q0 = __half22float2(p0);
        float2 q1 = __half22float2(p1);
        float2 q2 = __half22float2(p2);
        float2 q3 = __half22float2(p3);
        acc0 += q0.x; acc1 += q0.y; acc2 += q1.x; acc3 += q1.y;
        acc4 += q2.x; acc5 += q2.y; acc6 += q3.x; acc7 += q3.y;
    }
    // reduce across the 8 slot-groups (lane bits 3,4,5)
#pragma unroll
    for (int off = 8; off <= 32; off <<= 1) {
        acc0 += __shfl_xor(acc0, off);
        acc1 += __shfl_xor(acc1, off);
        acc2 += __shfl_xor(acc2, off);
        acc3 += __shfl_xor(acc3, off);
        acc4 += __shfl_xor(acc4, off);
        acc5 += __shfl_xor(acc5, off);
        acc6 += __shfl_xor(acc6, off);
        acc7 += __shfl_xor(acc7, off);
    }
    float r = dis[d];
    if (g == 0) {
        __half2 o0 = __floats2half2_rn(r * acc0, r * acc1);
        __half2 o1 = __floats2half2_rn(r * acc2, r * acc3);
        __half2 o2 = __floats2half2_rn(r * acc4, r * acc5);
        __half2 o3 = __floats2half2_rn(r * acc6, r * acc7);
        uint4 w;
        w.x = *(unsigned*)&o0; w.y = *(unsigned*)&o1;
        w.z = *(unsigned*)&o2; w.w = *(unsigned*)&o3;
        *(uint4*)(a2h + (size_t)d * 64 + f * 8) = w;
    }
}

// ---- h1 (all-MFMA): out = softmax(elu(elu(a2h@W2)@Wm1)@Wm2) ----
__global__ __launch_bounds__(256) void h1_kernel(const __half* __restrict__ a2h,
    const __half* __restrict__ W2t, const float* __restrict__ b2g,
    const __half* __restrict__ Wm1t, const float* __restrict__ bm1g,
    const __half* __restrict__ Wm2p, const float* __restrict__ bm2g,
    float* __restrict__ out, int N) {
    __shared__ __align__(16) __half h2s[64 * H2P];   // 11.3 KB
    __shared__ __align__(16) __half ms[64 * MSP2];   // 17.4 KB
    int tid = threadIdx.x;
    int wave = tid >> 6, lane = tid & 63;
    int q = lane >> 4, l16 = lane & 15;
    int base = blockIdx.x * 64;

    v8hf wc[4];
#pragma unroll
    for (int t = 0; t < 4; ++t)
        wc[t] = *(const v8hf*)(Wm2p + ((size_t)(t * 64 + lane)) * 8);
    float bbc = (l16 < 15) ? bm2g[l16] : 0.f;

    // ---- stage A: D[m=node16][n=f] = a2h @ W2 ----
    {
        int nodeRow = base + wave * 16 + l16;
        size_t arow = (size_t)min(nodeRow, N - 1) * 64;
        v8hf af0 = *(const v8hf*)(a2h + arow + q * 8);
        v8hf af1 = *(const v8hf*)(a2h + arow + 32 + q * 8);
#pragma unroll
        for (int fb = 0; fb < 4; ++fb) {
            float bb = b2g[fb * 16 + l16];
            v4f acc = {bb, bb, bb, bb};
            v8hf b0 = *(const v8hf*)(W2t + (fb * 16 + l16) * 64 + q * 8);
            v8hf b1 = *(const v8hf*)(W2t + (fb * 16 + l16) * 64 + 32 + q * 8);
            acc = __builtin_amdgcn_mfma_f32_16x16x32_f16(af0, b0, acc, 0, 0, 0);
            acc = __builtin_amdgcn_mfma_f32_16x16x32_f16(af1, b1, acc, 0, 0, 0);
#pragma unroll
            for (int r = 0; r < 4; ++r)
                h2s[(wave * 16 + q * 4 + r) * H2P + fb * 16 + l16] =
                    __float2half(elu(acc[r]));
        }
    }
    __syncthreads();
    // ---- stage B: D[m=node16][n=j] = h2 @ Wm1 ----
    {
        int arow = (wave * 16 + l16) * H2P;
        v8hf af0 = *(const v8hf*)(h2s + arow + q * 8);
        v8hf af1 = *(const v8hf*)(h2s + arow + 32 + q * 8);
#pragma unroll
        for (int jb = 0; jb < 8; ++jb) {
            float bb = bm1g[jb * 16 + l16];
            v4f acc = {bb, bb, bb, bb};
            v8hf b0 = *(const v8hf*)(Wm1t + (jb * 16 + l16) * 64 + q * 8);
            v8hf b1 = *(const v8hf*)(Wm1t + (jb * 16 + l16) * 64 + 32 + q * 8);
            acc = __builtin_amdgcn_mfma_f32_16x16x32_f16(af0, b0, acc, 0, 0, 0);
            acc = __builtin_amdgcn_mfma_f32_16x16x32_f16(af1, b1, acc, 0, 0, 0);
#pragma unroll
            for (int r = 0; r < 4; ++r)
                ms[(wave * 16 + q * 4 + r) * MSP2 + jb * 16 + l16] =
                    __float2half(elu(acc[r]));
        }
    }
    __syncthreads();
    // ---- stage C: D[m=node16][n=class16] = m @ Wm2 (K=128), shfl softmax ----
    {
        int arow = (wave * 16 + l16) * MSP2;
        v4f accC = {bbc, bbc, bbc, bbc};
#pragma unroll
        for (int t = 0; t < 4; ++t) {
            v8hf a = *(const v8hf*)(ms + arow + t * 32 + q * 8);
            accC = __builtin_amdgcn_mfma_f32_16x16x32_f16(a, wc[t], accC, 0, 0, 0);
        }
#pragma unroll
        for (int r = 0; r < 4; ++r) {
            float lg = (l16 < 15) ? accC[r] : -1e30f;
            float mx = lg;
            mx = fmaxf(mx, __shfl_xor(mx, 1));
            mx = fmaxf(mx, __shfl_xor(mx, 2));
            mx = fmaxf(mx, __shfl_xor(mx, 4));
            mx = fmaxf(mx, __shfl_xor(mx, 8));
            float ex = (l16 < 15) ? __expf(lg - mx) : 0.f;
            float sden = ex;
            sden += __shfl_xor(sden, 1);
            sden += __shfl_xor(sden, 2);
            sden += __shfl_xor(sden, 4);
            sden += __shfl_xor(sden, 8);
            int node = base + wave * 16 + q * 4 + r;
            if (l16 < 15 && node < N)
                out[(size_t)node * 15 + l16] = ex / sden;
        }
    }
}

extern "C" void kernel_launch(void* const* d_in, const int* in_sizes, int n_in,
                              void* d_out, int out_size, void* d_ws, size_t ws_size,
                              hipStream_t stream) {
    const float* x   = (const float*)d_in[0];
    const int*   ei  = (const int*)d_in[1];
    const float* W1  = (const float*)d_in[2];
    const float* b1  = (const float*)d_in[3];
    const float* W2  = (const float*)d_in[4];
    const float* b2  = (const float*)d_in[5];
    const float* Wm1 = (const float*)d_in[6];
    const float* bm1 = (const float*)d_in[7];
    const float* Wm2 = (const float*)d_in[8];
    const float* bm2 = (const float*)d_in[9];
    float* out = (float*)d_out;

    int N = in_sizes[0] / 3;
    int E = in_sizes[1] / 2;
    const int* src = ei;
    const int* dst = ei + E;
    int NBK = (N + SPAN - 1) / SPAN;   // 782

    uintptr_t p = (uintptr_t)d_ws;
    auto carve = [&](size_t bytes) -> void* {
        p = (p + 255) & ~(uintptr_t)255;
        void* r = (void*)p;
        p += bytes;
        return r;
    };
    // colb padded +64 ints: agg64 reads up to slot-chunk overrun (masked)
    unsigned* colb    = (unsigned*)carve((size_t)NBK * CAP * 4 + 256);
    __half*   a2h     = (__half*)carve((size_t)N * 64 * 2);
    __half*   s1h     = (__half*)carve((size_t)N * 64 * 2);
    int*      cursor  = (int*)carve((size_t)NBK * 4);
    uint2*    rp2     = (uint2*)carve((size_t)N * 8);
    float*    dis     = (float*)carve((size_t)N * 4);
    __half*   sxh     = (__half*)carve((size_t)N * 8);
    __half*   W2t     = (__half*)carve(64 * 64 * 2);
    __half*   Wm1t    = (__half*)carve(128 * 64 * 2);
    __half*   Wm2p    = (__half*)carve(4 * 64 * 8 * 2);

    int nChunks = (E + CH - 1) / CH;          // 391
    int aggBlocks = (N + 7) / 8;              // agg3: 2 nodes/wave, 4 waves/block
    int aggBlocks64 = (N + 3) / 4;            // agg64: 1 node/wave, 4 waves/block
    int nTiles = (N + 63) / 64;               // h1: 64-node tiles

    hipMemsetAsync(cursor, 0, (size_t)NBK * 4, stream);
    scatter_kernel<<<nChunks + 1, 512, 0, stream>>>(src, dst, cursor, colb,
        W2, Wm1, Wm2, W2t, Wm1t, Wm2p, E, NBK, nChunks);
    csr_sort_kernel<<<NBK, 512, 0, stream>>>(colb, cursor, x, rp2, dis, sxh, N);
    agg3_kernel<<<aggBlocks, 256, 0, stream>>>(sxh, rp2, colb, dis, W1, b1, s1h, N);
    agg64_kernel<<<aggBlocks64, 256, 0, stream>>>(s1h, rp2, colb, dis, a2h, N);
    h1_kernel<<<nTiles, 256, 0, stream>>>(a2h, W2t, b2, Wm1t, bm1, Wm2p, bm2, out, N);
}

// Round 2
// 231.792 us; speedup vs baseline: 1.0399x; 1.0053x over previous
//
#include <hip/hip_runtime.h>
#include <hip/hip_fp16.h>
#include <math.h>

// ---------------------------------------------------------------------------
// GNN pool: 2x GCNConv(elu) + MLP(128) + Linear(15) + softmax
// N=100000, E=3200000, IN=3, HID=64, MLP_HID=128, K=15, fp32 in/out.
//
// Round-16 pipeline (6 dispatches incl. memset):
//   memset cursor -> scatter512 (+prep block) -> csr_sort512 -> agg3
//   -> agg64 (r15 structure + NEW: explicit 2-deep software pipeline)
//   -> h1 (all-MFMA + shfl softmax, r13)
//
// r16 theory: r15 (8 edges/gather-instr) gave 62->55us but VGPR stayed 20
// -> compiler register-recycled A/B: only 2 gathers in flight per wave,
// colb->gather chain re-serialized every 16-slot chunk. This round issues
// chunk p+1's colb + both dwordx4 gathers BEFORE consuming chunk p
// (copy-out pattern, static indexing only). 4 gathers in flight, next
// chunk's colb latency hidden under current chunk's consume.
// Predicted: agg64 55->38-45us, VGPR ~40, VALUBusy 62-72%, FETCH flat.
// Falsifier: flat dur with VGPR~40 => L2-miss/L3 path ceiling (~3.2TB/s)
// => next round: src-partitioned L2-resident aggregation.
// ---------------------------------------------------------------------------

#define SPAN 128          // nodes per bucket
#define CAP  4608         // bucket capacity (mean 4092 + ~8 sigma)
#define CH   8192         // edges per scatter chunk (391 chunks)
#define EPT  16           // edges per thread in scatter (512 threads)
#define H2P  88           // h2s row pad (halfs)
#define MSP2 136          // ms row pad (halfs)

typedef _Float16 v8hf __attribute__((ext_vector_type(8)));
typedef float    v4f  __attribute__((ext_vector_type(4)));

__device__ __forceinline__ float elu(float v) { return v > 0.f ? v : expm1f(v); }

// ---- scatter (512 thr): edges -> buckets by dst>>7; last block = weight prep ----
__global__ __launch_bounds__(512) void scatter_kernel(const int* __restrict__ src,
    const int* __restrict__ dst, int* __restrict__ cursor, unsigned* __restrict__ colb,
    const float* __restrict__ W2, const float* __restrict__ Wm1,
    const float* __restrict__ Wm2, __half* __restrict__ W2t,
    __half* __restrict__ Wm1t, __half* __restrict__ Wm2p,
    int E, int NBK, int nChunks) {
    int tid = threadIdx.x;
    if ((int)blockIdx.x == nChunks) {   // ---- prep block ----
        for (int i = tid; i < 64 * 64; i += 512) {
            int f = i >> 6, k = i & 63;
            W2t[f * 64 + k] = __float2half(W2[k * 64 + f]);
        }
        for (int i = tid; i < 128 * 64; i += 512) {
            int j = i >> 6, f = i & 63;
            Wm1t[j * 64 + f] = __float2half(Wm1[f * 128 + j]);
        }
        for (int i = tid; i < 4 * 64 * 8; i += 512) {
            int j = i & 7, l = (i >> 3) & 63, t = i >> 9;
            int k = t * 32 + (l >> 4) * 8 + j;
            int c = l & 15;
            Wm2p[i] = (c < 15) ? __float2half(Wm2[k * 15 + c]) : __half(0.f);
        }
        return;
    }
    __shared__ int hist[1024];
    __shared__ unsigned gb[1024];
    int chunk = blockIdx.x;
    for (int i = tid; i < NBK; i += 512) hist[i] = 0;
    __syncthreads();
    int base = chunk * CH;
    int cnt = min(CH, E - base);
    unsigned br[EPT], dt[EPT];
#pragma unroll
    for (int j = 0; j < EPT; ++j) {
        int idx = j * 512 + tid;
        br[j] = 0xFFFFFFFFu;
        if (idx < cnt) {
            int e = base + idx;
            int s = src[e], d = dst[e];
            int b = d >> 7;
            int r = atomicAdd(&hist[b], 1);
            br[j] = ((unsigned)b << 13) | (unsigned)r;   // b<1024(10b), r<8192(13b)
            dt[j] = ((unsigned)(d & 127) << 17) | (unsigned)s;
        }
    }
    __syncthreads();
    for (int b = tid; b < NBK; b += 512) {
        int c = hist[b];
        gb[b] = (unsigned)(b * CAP) + (c ? (unsigned)atomicAdd(&cursor[b], c) : 0u);
    }
    __syncthreads();
#pragma unroll
    for (int j = 0; j < EPT; ++j) {
        if (br[j] != 0xFFFFFFFFu) {
            int b = br[j] >> 13;
            int r = br[j] & 8191;
            unsigned pos = gb[b] + (unsigned)r;
            if (pos < (unsigned)(b + 1) * CAP) colb[pos] = dt[j];
        }
    }
}

// ---- per-bucket counting sort IN PLACE (padded layout), rp2, dis, sxh ----
__global__ __launch_bounds__(512) void csr_sort_kernel(unsigned* __restrict__ colb,
    const int* __restrict__ cursor, const float* __restrict__ x,
    uint2* __restrict__ rp2, float* __restrict__ dis, __half* __restrict__ sxh,
    int N) {
    __shared__ __align__(16) unsigned ebuf[CAP];
    __shared__ __align__(16) int sbuf[CAP];
    __shared__ int cnt[SPAN], pref[SPAN], fill[SPAN];
    int b = blockIdx.x, tid = threadIdx.x;
    int n = min(cursor[b], CAP);
    size_t base = (size_t)b * CAP;
    if (tid < SPAN) cnt[tid] = 0;
    int n4 = n >> 2;
    for (int k = tid; k < n4; k += 512)
        *(uint4*)(ebuf + 4 * k) = *(const uint4*)(colb + base + 4 * k);
    for (int i = (n4 << 2) + tid; i < n; i += 512) ebuf[i] = colb[base + i];
    __syncthreads();
    for (int i = tid; i < n; i += 512) atomicAdd(&cnt[(ebuf[i] >> 17) & 127], 1);
    __syncthreads();
    if (tid < SPAN) pref[tid] = cnt[tid];
    __syncthreads();
    for (int off = 1; off < SPAN; off <<= 1) {
        int xv = (tid < SPAN && tid >= off) ? pref[tid - off] : 0;
        __syncthreads();
        if (tid < SPAN) pref[tid] += xv;
        __syncthreads();
    }
    if (tid < SPAN) {
        int ex = pref[tid] - cnt[tid];
        fill[tid] = ex;
        int node = b * SPAN + tid;
        if (node < N) {
            uint2 rp;
            rp.x = (unsigned)(base + ex);
            rp.y = (unsigned)(base + ex + cnt[tid]);
            rp2[node] = rp;
            float r = rsqrtf((float)(cnt[tid] + 1));
            dis[node] = r;
            __half2 h0 = __floats2half2_rn(r * x[node * 3 + 0], r * x[node * 3 + 1]);
            __half2 h1 = __floats2half2_rn(r * x[node * 3 + 2], 0.f);
            uint2 w; w.x = *(unsigned*)&h0; w.y = *(unsigned*)&h1;
            *(uint2*)(sxh + (size_t)node * 4) = w;
        }
    }
    __syncthreads();
    for (int i = tid; i < n; i += 512) {
        unsigned e = ebuf[i];
        int pos = atomicAdd(&fill[(e >> 17) & 127], 1);
        sbuf[pos] = (int)(e & 0x1FFFF);
    }
    __syncthreads();
    for (int k = tid; k < n4; k += 512)
        *(uint4*)(colb + base + 4 * k) = *(const uint4*)(sbuf + 4 * k);
    for (int i = (n4 << 2) + tid; i < n; i += 512) colb[base + i] = (unsigned)sbuf[i];
}

// ---- layer 1: 2 nodes/wave (32 lanes each), 8B gathers; s1h fp16 ----
__global__ void agg3_kernel(const __half* __restrict__ sxh, const uint2* __restrict__ rp2,
                            const unsigned* __restrict__ colb, const float* __restrict__ dis,
                            const float* __restrict__ W1, const float* __restrict__ b1,
                            __half* __restrict__ s1h, int N) {
    int wave = (blockIdx.x * blockDim.x + threadIdx.x) >> 6;
    int lane = threadIdx.x & 63;
    int hl = lane & 31;
    int d = wave * 2 + (lane >> 5);
    bool act = d < N;
    int start = 0, end = 0;
    if (act) { uint2 rp = rp2[d]; start = (int)rp.x; end = (int)rp.y; }
    float a0 = 0.f, a1 = 0.f, a2v = 0.f;
    for (int i = start + hl; i < end; i += 32) {
        uint2 rq = *(const uint2*)(sxh + (size_t)colb[i] * 4);
        float2 u0 = __half22float2(*(__half2*)&rq.x);
        float2 u1 = __half22float2(*(__half2*)&rq.y);
        a0 += u0.x; a1 += u0.y; a2v += u1.x;
    }
#pragma unroll
    for (int off = 16; off; off >>= 1) {
        a0  += __shfl_xor(a0, off);
        a1  += __shfl_xor(a1, off);
        a2v += __shfl_xor(a2v, off);
    }
    if (act) {
        uint2 rq = *(const uint2*)(sxh + (size_t)d * 4);   // self loop
        float2 u0 = __half22float2(*(__half2*)&rq.x);
        float2 u1 = __half22float2(*(__half2*)&rq.y);
        a0 += u0.x; a1 += u0.y; a2v += u1.x;
        float r = dis[d];
        float v0 = r * (a0 * W1[hl]      + a1 * W1[64 + hl]      + a2v * W1[128 + hl])      + b1[hl];
        float v1 = r * (a0 * W1[32 + hl] + a1 * W1[96 + hl]      + a2v * W1[160 + hl])      + b1[32 + hl];
        s1h[(size_t)d * 64 + hl]      = __float2half(r * elu(v0));
        s1h[(size_t)d * 64 + 32 + hl] = __float2half(r * elu(v1));
    }
}

// ---- layer 2 (r16): 1 node/wave; lane = 8*slot + octet; dwordx4 row gathers ----
// 2-deep software pipeline: chunk p+1's colb + gathers issue before chunk p
// is consumed. 4 gathers in flight per wave (was 2 with compiler recycling).
__global__ void agg64_kernel(const __half* __restrict__ s1h, const uint2* __restrict__ rp2,
                             const unsigned* __restrict__ colb, const float* __restrict__ dis,
                             __half* __restrict__ a2h, int N) {
    int wave = (blockIdx.x * blockDim.x + threadIdx.x) >> 6;
    int lane = threadIdx.x & 63;
    int g = lane >> 3;          // edge slot within chunk (0..7)
    int f = lane & 7;           // feature octet: halfs f*8 .. f*8+7 (16B)
    int d = wave;
    if (d >= N) return;
    uint2 rp = rp2[d];
    int start = (int)rp.x;
    int ne = (int)(rp.y - rp.x);       // real in-edges
    int nslots = ne + 1;               // + self loop at slot ne
    int npair = (nslots + 15) >> 4;    // 16-slot pair-chunks
    float acc0 = 0.f, acc1 = 0.f, acc2 = 0.f, acc3 = 0.f;
    float acc4 = 0.f, acc5 = 0.f, acc6 = 0.f, acc7 = 0.f;

    // ---- prologue: issue chunk 0 ----
    int ja = g, jb = g + 8;
    int ca = (int)colb[start + ja];
    int cb = (int)colb[start + jb];
    bool oa = ja < nslots, ob = jb < nslots;
    ca = (ja < ne) ? ca : d;           // slot ne -> self; beyond -> safe dummy
    cb = (jb < ne) ? cb : d;
    uint4 A = *(const uint4*)(s1h + (size_t)ca * 64 + f * 8);
    uint4 B = *(const uint4*)(s1h + (size_t)cb * 64 + f * 8);

    for (int p = 0; p < npair; ++p) {
        // take current chunk into locals (register renames, free)
        uint4 Ac = A, Bc = B;
        bool oac = oa, obc = ob;
        // ---- issue chunk p+1 before consuming chunk p ----
        if (p + 1 < npair) {
            int ja2 = (p + 1) * 16 + g, jb2 = ja2 + 8;
            int ca2 = (int)colb[start + ja2];
            int cb2 = (int)colb[start + jb2];
            oa = ja2 < nslots; ob = jb2 < nslots;
            ca2 = (ja2 < ne) ? ca2 : d;
            cb2 = (jb2 < ne) ? cb2 : d;
            A = *(const uint4*)(s1h + (size_t)ca2 * 64 + f * 8);
            B = *(const uint4*)(s1h + (size_t)cb2 * 64 + f * 8);
        }
        // ---- consume chunk p ----
        Ac.x = oac ? Ac.x : 0u; Ac.y = oac ? Ac.y : 0u;
        Ac.z = oac ? Ac.z : 0u; Ac.w = oac ? Ac.w : 0u;
        Bc.x = obc ? Bc.x : 0u; Bc.y = obc ? Bc.y : 0u;
        Bc.z = obc ? Bc.z : 0u; Bc.w = obc ? Bc.w : 0u;
        __half2 p0 = __hadd2(*(__half2*)&Ac.x, *(__half2*)&Bc.x);
        __half2 p1 = __hadd2(*(__half2*)&Ac.y, *(__half2*)&Bc.y);
        __half2 p2 = __hadd2(*(__half2*)&Ac.z, *(__half2*)&Bc.z);
        __half2 p3 = __hadd2(*(__half2*)&Ac.w, *(__half2*)&Bc.w);
        float2 q0 = __half22float2(p0);
        float2 q1 = __half22float2(p1);
        float2 q2 = __half22float2(p2);
        float2 q3 = __half22float2(p3);
        acc0 += q0.x; acc1 += q0.y; acc2 += q1.x; acc3 += q1.y;
        acc4 += q2.x; acc5 += q2.y; acc6 += q3.x; acc7 += q3.y;
    }
    // reduce across the 8 slot-groups (lane bits 3,4,5)
#pragma unroll
    for (int off = 8; off <= 32; off <<= 1) {
        acc0 += __shfl_xor(acc0, off);
        acc1 += __shfl_xor(acc1, off);
        acc2 += __shfl_xor(acc2, off);
        acc3 += __shfl_xor(acc3, off);
        acc4 += __shfl_xor(acc4, off);
        acc5 += __shfl_xor(acc5, off);
        acc6 += __shfl_xor(acc6, off);
        acc7 += __shfl_xor(acc7, off);
    }
    float r = dis[d];
    if (g == 0) {
        __half2 o0 = __floats2half2_rn(r * acc0, r * acc1);
        __half2 o1 = __floats2half2_rn(r * acc2, r * acc3);
        __half2 o2 = __floats2half2_rn(r * acc4, r * acc5);
        __half2 o3 = __floats2half2_rn(r * acc6, r * acc7);
        uint4 w;
        w.x = *(unsigned*)&o0; w.y = *(unsigned*)&o1;
        w.z = *(unsigned*)&o2; w.w = *(unsigned*)&o3;
        *(uint4*)(a2h + (size_t)d * 64 + f * 8) = w;
    }
}

// ---- h1 (all-MFMA): out = softmax(elu(elu(a2h@W2)@Wm1)@Wm2) ----
__global__ __launch_bounds__(256) void h1_kernel(const __half* __restrict__ a2h,
    const __half* __restrict__ W2t, const float* __restrict__ b2g,
    const __half* __restrict__ Wm1t, const float* __restrict__ bm1g,
    const __half* __restrict__ Wm2p, const float* __restrict__ bm2g,
    float* __restrict__ out, int N) {
    __shared__ __align__(16) __half h2s[64 * H2P];   // 11.3 KB
    __shared__ __align__(16) __half ms[64 * MSP2];   // 17.4 KB
    int tid = threadIdx.x;
    int wave = tid >> 6, lane = tid & 63;
    int q = lane >> 4, l16 = lane & 15;
    int base = blockIdx.x * 64;

    v8hf wc[4];
#pragma unroll
    for (int t = 0; t < 4; ++t)
        wc[t] = *(const v8hf*)(Wm2p + ((size_t)(t * 64 + lane)) * 8);
    float bbc = (l16 < 15) ? bm2g[l16] : 0.f;

    // ---- stage A: D[m=node16][n=f] = a2h @ W2 ----
    {
        int nodeRow = base + wave * 16 + l16;
        size_t arow = (size_t)min(nodeRow, N - 1) * 64;
        v8hf af0 = *(const v8hf*)(a2h + arow + q * 8);
        v8hf af1 = *(const v8hf*)(a2h + arow + 32 + q * 8);
#pragma unroll
        for (int fb = 0; fb < 4; ++fb) {
            float bb = b2g[fb * 16 + l16];
            v4f acc = {bb, bb, bb, bb};
            v8hf b0 = *(const v8hf*)(W2t + (fb * 16 + l16) * 64 + q * 8);
            v8hf b1 = *(const v8hf*)(W2t + (fb * 16 + l16) * 64 + 32 + q * 8);
            acc = __builtin_amdgcn_mfma_f32_16x16x32_f16(af0, b0, acc, 0, 0, 0);
            acc = __builtin_amdgcn_mfma_f32_16x16x32_f16(af1, b1, acc, 0, 0, 0);
#pragma unroll
            for (int r = 0; r < 4; ++r)
                h2s[(wave * 16 + q * 4 + r) * H2P + fb * 16 + l16] =
                    __float2half(elu(acc[r]));
        }
    }
    __syncthreads();
    // ---- stage B: D[m=node16][n=j] = h2 @ Wm1 ----
    {
        int arow = (wave * 16 + l16) * H2P;
        v8hf af0 = *(const v8hf*)(h2s + arow + q * 8);
        v8hf af1 = *(const v8hf*)(h2s + arow + 32 + q * 8);
#pragma unroll
        for (int jb = 0; jb < 8; ++jb) {
            float bb = bm1g[jb * 16 + l16];
            v4f acc = {bb, bb, bb, bb};
            v8hf b0 = *(const v8hf*)(Wm1t + (jb * 16 + l16) * 64 + q * 8);
            v8hf b1 = *(const v8hf*)(Wm1t + (jb * 16 + l16) * 64 + 32 + q * 8);
            acc = __builtin_amdgcn_mfma_f32_16x16x32_f16(af0, b0, acc, 0, 0, 0);
            acc = __builtin_amdgcn_mfma_f32_16x16x32_f16(af1, b1, acc, 0, 0, 0);
#pragma unroll
            for (int r = 0; r < 4; ++r)
                ms[(wave * 16 + q * 4 + r) * MSP2 + jb * 16 + l16] =
                    __float2half(elu(acc[r]));
        }
    }
    __syncthreads();
    // ---- stage C: D[m=node16][n=class16] = m @ Wm2 (K=128), shfl softmax ----
    {
        int arow = (wave * 16 + l16) * MSP2;
        v4f accC = {bbc, bbc, bbc, bbc};
#pragma unroll
        for (int t = 0; t < 4; ++t) {
            v8hf a = *(const v8hf*)(ms + arow + t * 32 + q * 8);
            accC = __builtin_amdgcn_mfma_f32_16x16x32_f16(a, wc[t], accC, 0, 0, 0);
        }
#pragma unroll
        for (int r = 0; r < 4; ++r) {
            float lg = (l16 < 15) ? accC[r] : -1e30f;
            float mx = lg;
            mx = fmaxf(mx, __shfl_xor(mx, 1));
            mx = fmaxf(mx, __shfl_xor(mx, 2));
            mx = fmaxf(mx, __shfl_xor(mx, 4));
            mx = fmaxf(mx, __shfl_xor(mx, 8));
            float ex = (l16 < 15) ? __expf(lg - mx) : 0.f;
            float sden = ex;
            sden += __shfl_xor(sden, 1);
            sden += __shfl_xor(sden, 2);
            sden += __shfl_xor(sden, 4);
            sden += __shfl_xor(sden, 8);
            int node = base + wave * 16 + q * 4 + r;
            if (l16 < 15 && node < N)
                out[(size_t)node * 15 + l16] = ex / sden;
        }
    }
}

extern "C" void kernel_launch(void* const* d_in, const int* in_sizes, int n_in,
                              void* d_out, int out_size, void* d_ws, size_t ws_size,
                              hipStream_t stream) {
    const float* x   = (const float*)d_in[0];
    const int*   ei  = (const int*)d_in[1];
    const float* W1  = (const float*)d_in[2];
    const float* b1  = (const float*)d_in[3];
    const float* W2  = (const float*)d_in[4];
    const float* b2  = (const float*)d_in[5];
    const float* Wm1 = (const float*)d_in[6];
    const float* bm1 = (const float*)d_in[7];
    const float* Wm2 = (const float*)d_in[8];
    const float* bm2 = (const float*)d_in[9];
    float* out = (float*)d_out;

    int N = in_sizes[0] / 3;
    int E = in_sizes[1] / 2;
    const int* src = ei;
    const int* dst = ei + E;
    int NBK = (N + SPAN - 1) / SPAN;   // 782

    uintptr_t p = (uintptr_t)d_ws;
    auto carve = [&](size_t bytes) -> void* {
        p = (p + 255) & ~(uintptr_t)255;
        void* r = (void*)p;
        p += bytes;
        return r;
    };
    // colb padded +64 ints: agg64 reads up to slot-chunk overrun (masked)
    unsigned* colb    = (unsigned*)carve((size_t)NBK * CAP * 4 + 256);
    __half*   a2h     = (__half*)carve((size_t)N * 64 * 2);
    __half*   s1h     = (__half*)carve((size_t)N * 64 * 2);
    int*      cursor  = (int*)carve((size_t)NBK * 4);
    uint2*    rp2     = (uint2*)carve((size_t)N * 8);
    float*    dis     = (float*)carve((size_t)N * 4);
    __half*   sxh     = (__half*)carve((size_t)N * 8);
    __half*   W2t     = (__half*)carve(64 * 64 * 2);
    __half*   Wm1t    = (__half*)carve(128 * 64 * 2);
    __half*   Wm2p    = (__half*)carve(4 * 64 * 8 * 2);

    int nChunks = (E + CH - 1) / CH;          // 391
    int aggBlocks = (N + 7) / 8;              // agg3: 2 nodes/wave, 4 waves/block
    int aggBlocks64 = (N + 3) / 4;            // agg64: 1 node/wave, 4 waves/block
    int nTiles = (N + 63) / 64;               // h1: 64-node tiles

    hipMemsetAsync(cursor, 0, (size_t)NBK * 4, stream);
    scatter_kernel<<<nChunks + 1, 512, 0, stream>>>(src, dst, cursor, colb,
        W2, Wm1, Wm2, W2t, Wm1t, Wm2p, E, NBK, nChunks);
    csr_sort_kernel<<<NBK, 512, 0, stream>>>(colb, cursor, x, rp2, dis, sxh, N);
    agg3_kernel<<<aggBlocks, 256, 0, stream>>>(sxh, rp2, colb, dis, W1, b1, s1h, N);
    agg64_kernel<<<aggBlocks64, 256, 0, stream>>>(s1h, rp2, colb, dis, a2h, N);
    h1_kernel<<<nTiles, 256, 0, stream>>>(a2h, W2t, b2, Wm1t, bm1, Wm2p, bm2, out, N);
}